// Round 1
// baseline (18.638 us; speedup 1.0000x reference)
//
#include <hip/hip_runtime.h>

#define NB 65536
#define NN 128
#define FDIM 16
#define ODIM 64

typedef __attribute__((ext_vector_type(8))) short s16x8;
typedef __attribute__((ext_vector_type(4))) float f32x4;

__device__ __forceinline__ unsigned short f2bf(float f) {
    unsigned u = __builtin_bit_cast(unsigned, f);
    u += 0x7FFFu + ((u >> 16) & 1u);
    return (unsigned short)(u >> 16);
}
__device__ __forceinline__ float bf2f(unsigned short h) {
    unsigned u = ((unsigned)h) << 16;
    return __builtin_bit_cast(float, u);
}

// ---------------------------------------------------------------------------
// Kernel 1: build W' = 0.5 * S (symmetric, zero diagonal) in bf16, stored
// directly in MFMA B-fragment order: wfrag[((nt*4+kt)*64 + lane)*8 + e]
// holds W'[k][n] with k = kt*32 + (lane>>4)*8 + e, n = nt*16 + (lane&15).
// ---------------------------------------------------------------------------
__global__ void prep_w(const float* __restrict__ kern, const int* __restrict__ fd,
                       unsigned short* __restrict__ wfrag) {
    int i = blockIdx.x;    // K index of W[k][n]
    int j = threadIdx.x;   // N index
    int fi = fd[i], fj = fd[j];
    const float4* a = (const float4*)(kern + (i * FDIM + fj) * ODIM);
    const float4* b = (const float4*)(kern + (j * FDIM + fi) * ODIM);
    float s = 0.f;
#pragma unroll
    for (int k = 0; k < ODIM / 4; ++k) {
        float4 av = a[k], bv = b[k];
        s += av.x * bv.x + av.y * bv.y + av.z * bv.z + av.w * bv.w;
    }
    float w = (i == j) ? 0.f : 0.5f * s;
    int kt = i >> 5, kc = (i >> 3) & 3, e = i & 7;
    int nt = j >> 4;
    int lane = kc * 16 + (j & 15);
    wfrag[((nt * 4 + kt) * 64 + lane) * 8 + e] = f2bf(w);
}

// ---------------------------------------------------------------------------
// Kernel 2: out[b] = x_b^T W' x_b via MFMA.
// Block = 256 threads = 4 waves; each wave owns a 16-row tile of x.
// Y = Xh*W + Xl*W (two bf16 MFMA passes, fp32 accum), then per-row dot with
// x (bf16-hi staged in LDS) and a 16-lane shuffle reduction.
// ---------------------------------------------------------------------------
__global__ __launch_bounds__(256) void qform(const float* __restrict__ x,
                                             const unsigned short* __restrict__ wfrag,
                                             float* __restrict__ out) {
    __shared__ __align__(16) unsigned short wlds[8 * 4 * 64 * 8];  // 32 KB
    __shared__ __align__(16) unsigned short xlds[4][16][136];      // 17 KB (bf16-hi of x)

    int tid = threadIdx.x;
    // cooperative copy of W fragments to LDS (32768 B = 2048 uint4)
    {
        const uint4* src = (const uint4*)wfrag;
        uint4* dst = (uint4*)wlds;
#pragma unroll
        for (int t = 0; t < 8; ++t) dst[t * 256 + tid] = src[t * 256 + tid];
    }

    int wave = tid >> 6, lane = tid & 63;
    int row = lane & 15;       // M row within tile (A-fragment row)
    int kc = lane >> 4;        // K-chunk selector (A/B fragment k-group)
    int tile = blockIdx.x * 4 + wave;                 // 1024 blocks * 4 waves = 4096 tiles
    const float* xp = x + (tile * 16 + row) * NN;

    s16x8 ah[4], al[4];
#pragma unroll
    for (int kt = 0; kt < 4; ++kt) {
        const float4* p4 = (const float4*)(xp + kt * 32 + kc * 8);
        float4 v0 = p4[0], v1 = p4[1];
        float vs[8] = {v0.x, v0.y, v0.z, v0.w, v1.x, v1.y, v1.z, v1.w};
        unsigned short hb[8];
#pragma unroll
        for (int e = 0; e < 8; ++e) {
            hb[e] = f2bf(vs[e]);
            ah[kt][e] = (short)hb[e];
            float lo = vs[e] - bf2f(hb[e]);
            al[kt][e] = (short)f2bf(lo);
        }
        // stage bf16-hi of x for the epilogue (16B contiguous store)
        s16x8 hv;
#pragma unroll
        for (int e = 0; e < 8; ++e) hv[e] = (short)hb[e];
        *(s16x8*)&xlds[wave][row][kt * 32 + kc * 8] = hv;
    }
    __syncthreads();

    f32x4 acc[8];
#pragma unroll
    for (int nt = 0; nt < 8; ++nt) {
        f32x4 c = {0.f, 0.f, 0.f, 0.f};
#pragma unroll
        for (int kt = 0; kt < 4; ++kt) {
            s16x8 bf = *(const s16x8*)&wlds[((nt * 4 + kt) * 64 + lane) * 8];
            c = __builtin_amdgcn_mfma_f32_16x16x32_bf16(ah[kt], bf, c, 0, 0, 0);
            c = __builtin_amdgcn_mfma_f32_16x16x32_bf16(al[kt], bf, c, 0, 0, 0);
        }
        acc[nt] = c;
    }

    // epilogue: out[m] = sum_n Y[m][n] * x[m][n]
    // D layout (m89-verified): col = lane&15, row = (lane>>4)*4 + reg
    int rg = lane >> 4, cl = lane & 15;
    float p0 = 0.f, p1 = 0.f, p2 = 0.f, p3 = 0.f;
#pragma unroll
    for (int nt = 0; nt < 8; ++nt) {
        int c0 = nt * 16 + cl;
        p0 += acc[nt][0] * bf2f(xlds[wave][rg * 4 + 0][c0]);
        p1 += acc[nt][1] * bf2f(xlds[wave][rg * 4 + 1][c0]);
        p2 += acc[nt][2] * bf2f(xlds[wave][rg * 4 + 2][c0]);
        p3 += acc[nt][3] * bf2f(xlds[wave][rg * 4 + 3][c0]);
    }
#pragma unroll
    for (int m = 1; m <= 8; m <<= 1) {
        p0 += __shfl_xor(p0, m, 64);
        p1 += __shfl_xor(p1, m, 64);
        p2 += __shfl_xor(p2, m, 64);
        p3 += __shfl_xor(p3, m, 64);
    }
    if (cl == 0) {
        int ob = tile * 16 + rg * 4;
        out[ob + 0] = p0;
        out[ob + 1] = p1;
        out[ob + 2] = p2;
        out[ob + 3] = p3;
    }
}

extern "C" void kernel_launch(void* const* d_in, const int* in_sizes, int n_in,
                              void* d_out, int out_size, void* d_ws, size_t ws_size,
                              hipStream_t stream) {
    const float* x = (const float*)d_in[0];
    const float* kern = (const float*)d_in[1];
    const int* fd = (const int*)d_in[2];
    float* out = (float*)d_out;
    unsigned short* wfrag = (unsigned short*)d_ws;  // 32 KB used

    prep_w<<<dim3(NN), dim3(NN), 0, stream>>>(kern, fd, wfrag);
    qform<<<dim3(NB / 64), dim3(256), 0, stream>>>(x, wfrag, out);
}

// Round 2
// 18.049 us; speedup vs baseline: 1.0326x; 1.0326x over previous
//
#include <hip/hip_runtime.h>

#define NB 65536
#define NN 128
#define FDIM 16
#define ODIM 64

typedef __attribute__((ext_vector_type(8))) short s16x8;
typedef __attribute__((ext_vector_type(4))) float f32x4;

typedef __attribute__((address_space(3))) void lds_void_t;
typedef const __attribute__((address_space(1))) void gbl_void_t;

__device__ __forceinline__ unsigned short f2bf_rne(float f) {
    unsigned u = __builtin_bit_cast(unsigned, f);
    u += 0x7FFFu + ((u >> 16) & 1u);
    return (unsigned short)(u >> 16);
}
__device__ __forceinline__ float bf2f(unsigned short h) {
    unsigned u = ((unsigned)h) << 16;
    return __builtin_bit_cast(float, u);
}

// ---------------------------------------------------------------------------
// Kernel 1: W' = 0.5*S (symmetric, zero diag), bf16, in MFMA B-fragment order:
// wfrag[((nt*4+kt)*64 + lane)*8 + e] = W'[k][n],
//   k = kt*32 + (lane>>4)*8 + e,  n = nt*16 + (lane&15).
// ILP: 4 independent accumulators (round-1 had a 128-deep serial FMA chain).
// ---------------------------------------------------------------------------
__global__ void prep_w(const float* __restrict__ kern, const int* __restrict__ fd,
                       unsigned short* __restrict__ wfrag) {
    int i = blockIdx.x;
    int j = threadIdx.x;
    int fi = fd[i], fj = fd[j];
    const float4* a = (const float4*)(kern + (i * FDIM + fj) * ODIM);
    const float4* b = (const float4*)(kern + (j * FDIM + fi) * ODIM);
    float s[4] = {0.f, 0.f, 0.f, 0.f};
#pragma unroll
    for (int k = 0; k < ODIM / 4; ++k) {
        float4 av = a[k], bv = b[k];
        s[k & 3] += av.x * bv.x + av.y * bv.y + av.z * bv.z + av.w * bv.w;
    }
    float w = (i == j) ? 0.f : 0.5f * (s[0] + s[1] + s[2] + s[3]);
    int kt = i >> 5, kc = (i >> 3) & 3, e = i & 7;
    int nt = j >> 4;
    int lane = kc * 16 + (j & 15);
    wfrag[((nt * 4 + kt) * 64 + lane) * 8 + e] = f2bf_rne(w);
}

// ---------------------------------------------------------------------------
// Kernel 2: out[b] = x_b^T W' x_b.
// 512 threads = 8 waves/block, each wave one 16-row tile; grid = 512 blocks
// = exactly 2 blocks/CU (LDS 66 KB) -> single block generation, no bubbles.
// W staged via async global_load_lds (linear layout matches, no VGPR trip).
// ---------------------------------------------------------------------------
__global__ __launch_bounds__(512, 4) void qform(const float* __restrict__ x,
                                                const unsigned short* __restrict__ wfrag,
                                                float* __restrict__ out) {
    __shared__ __align__(16) unsigned short wlds[8 * 4 * 64 * 8];  // 32 KB
    __shared__ __align__(16) unsigned short xlds[8][16][136];      // 34.8 KB

    int tid = threadIdx.x;
    int wave = tid >> 6, lane = tid & 63;

    // async W stage: 32 KB total, 4 chunks of 1 KB per wave (16 B/lane each)
    {
        const char* gsrc = (const char*)wfrag;
        char* ldst = (char*)wlds;
#pragma unroll
        for (int t = 0; t < 4; ++t) {
            int off = (wave * 4 + t) * 1024 + lane * 16;
            __builtin_amdgcn_global_load_lds((gbl_void_t*)(gsrc + off),
                                             (lds_void_t*)(ldst + off), 16, 0, 0);
        }
    }

    int row = lane & 15;   // A-fragment row within tile
    int kc = lane >> 4;    // K-chunk selector
    int tile = blockIdx.x * 8 + wave;  // 512 blocks * 8 waves = 4096 tiles
    const float* xp = x + (tile * 16 + row) * NN;

    s16x8 ah[4], al[4];
#pragma unroll
    for (int kt = 0; kt < 4; ++kt) {
        const float4* p4 = (const float4*)(xp + kt * 32 + kc * 8);
        float4 v0 = p4[0], v1 = p4[1];
        float vs[8] = {v0.x, v0.y, v0.z, v0.w, v1.x, v1.y, v1.z, v1.w};
        s16x8 hv;
#pragma unroll
        for (int e = 0; e < 8; ++e) {
            unsigned short hb = f2bf_rne(vs[e]);     // RNE hi
            hv[e] = (short)hb;
            ah[kt][e] = (short)hb;
            float lo = vs[e] - bf2f(hb);
            // trunc is enough for lo (residual ~2^-17 relative)
            al[kt][e] = (short)(unsigned short)(__builtin_bit_cast(unsigned, lo) >> 16);
        }
        *(s16x8*)&xlds[wave][row][kt * 32 + kc * 8] = hv;
    }
    __syncthreads();  // drains global_load_lds (vmcnt) + xlds writes

    f32x4 acc[8];
#pragma unroll
    for (int nt = 0; nt < 8; ++nt) {
        f32x4 c = {0.f, 0.f, 0.f, 0.f};
#pragma unroll
        for (int kt = 0; kt < 4; ++kt) {
            s16x8 bf = *(const s16x8*)&wlds[((nt * 4 + kt) * 64 + lane) * 8];
            c = __builtin_amdgcn_mfma_f32_16x16x32_bf16(ah[kt], bf, c, 0, 0, 0);
            c = __builtin_amdgcn_mfma_f32_16x16x32_bf16(al[kt], bf, c, 0, 0, 0);
        }
        acc[nt] = c;
    }

    // epilogue: out[m] = sum_n Y[m][n] * x[m][n]
    // D layout: col = lane&15, row = (lane>>4)*4 + reg  (m89-verified)
    int rg = lane >> 4, cl = lane & 15;
    float p0 = 0.f, p1 = 0.f, p2 = 0.f, p3 = 0.f;
#pragma unroll
    for (int nt = 0; nt < 8; ++nt) {
        int c0 = nt * 16 + cl;
        p0 += acc[nt][0] * bf2f(xlds[wave][rg * 4 + 0][c0]);
        p1 += acc[nt][1] * bf2f(xlds[wave][rg * 4 + 1][c0]);
        p2 += acc[nt][2] * bf2f(xlds[wave][rg * 4 + 2][c0]);
        p3 += acc[nt][3] * bf2f(xlds[wave][rg * 4 + 3][c0]);
    }
#pragma unroll
    for (int m = 1; m <= 8; m <<= 1) {
        p0 += __shfl_xor(p0, m, 64);
        p1 += __shfl_xor(p1, m, 64);
        p2 += __shfl_xor(p2, m, 64);
        p3 += __shfl_xor(p3, m, 64);
    }
    if (cl == 0) {
        int ob = tile * 16 + rg * 4;
        out[ob + 0] = p0;
        out[ob + 1] = p1;
        out[ob + 2] = p2;
        out[ob + 3] = p3;
    }
}

extern "C" void kernel_launch(void* const* d_in, const int* in_sizes, int n_in,
                              void* d_out, int out_size, void* d_ws, size_t ws_size,
                              hipStream_t stream) {
    const float* x = (const float*)d_in[0];
    const float* kern = (const float*)d_in[1];
    const int* fd = (const int*)d_in[2];
    float* out = (float*)d_out;
    unsigned short* wfrag = (unsigned short*)d_ws;  // 32 KB used

    prep_w<<<dim3(NN), dim3(NN), 0, stream>>>(kern, fd, wfrag);
    qform<<<dim3(512), dim3(512), 0, stream>>>(x, wfrag, out);
}